// Round 1
// baseline (7984.523 us; speedup 1.0000x reference)
//
#include <hip/hip_runtime.h>
#include <hip/hip_bf16.h>
#include <math.h>

// Problem constants
#define T_SEQ 4096
#define C_DIM 768
#define N_HEADS 12
#define D_HEAD 64
#define F_DIM 3072   // 4*C
#define EPS 1e-5f

// ---------------------------------------------------------------------------
// Tiled fp32 GEMM: C[M,N] = A[M,K] @ W[K,N] + bias[N], optional exact GELU.
// BM=BN=64, BK=16, 256 threads, 4x4 micro-tile per thread.
// All problem dims (4096, 768, 3072) divide the tile sizes -> no bounds checks.
// ---------------------------------------------------------------------------
#define BM 64
#define BN 64
#define BK 16

__launch_bounds__(256)
__global__ void gemm_bias_act(const float* __restrict__ A, const float* __restrict__ W,
                              const float* __restrict__ bias, float* __restrict__ C,
                              int M, int N, int K, int act) {
    __shared__ float As[BK][BM];   // A tile, transposed: As[k][m]
    __shared__ float Ws[BK][BN];   // W tile: Ws[k][n]

    const int tid = threadIdx.x;
    const int tx = tid & 15;        // 0..15 -> 4 cols each
    const int ty = tid >> 4;        // 0..15 -> 4 rows each
    const int bm = blockIdx.y * BM;
    const int bn = blockIdx.x * BN;

    float acc[4][4] = {};

    for (int k0 = 0; k0 < K; k0 += BK) {
        // Stage A tile: 64 rows x 16 k. One float4 along K per thread.
        {
            const int row = tid >> 2;            // 0..63
            const int kg  = (tid & 3) << 2;      // 0,4,8,12
            const float4 a4 = *reinterpret_cast<const float4*>(
                &A[(size_t)(bm + row) * K + k0 + kg]);
            As[kg + 0][row] = a4.x;
            As[kg + 1][row] = a4.y;
            As[kg + 2][row] = a4.z;
            As[kg + 3][row] = a4.w;
        }
        // Stage W tile: 16 k-rows x 64 cols. One float4 along N per thread.
        {
            const int wr = tid >> 4;             // 0..15
            const int wc = (tid & 15) << 2;      // 0..60
            *reinterpret_cast<float4*>(&Ws[wr][wc]) =
                *reinterpret_cast<const float4*>(&W[(size_t)(k0 + wr) * N + bn + wc]);
        }
        __syncthreads();

        #pragma unroll
        for (int kk = 0; kk < BK; ++kk) {
            const float4 a4 = *reinterpret_cast<const float4*>(&As[kk][ty << 2]);
            const float4 b4 = *reinterpret_cast<const float4*>(&Ws[kk][tx << 2]);
            const float av[4] = {a4.x, a4.y, a4.z, a4.w};
            const float bv[4] = {b4.x, b4.y, b4.z, b4.w};
            #pragma unroll
            for (int i = 0; i < 4; ++i)
                #pragma unroll
                for (int j = 0; j < 4; ++j)
                    acc[i][j] += av[i] * bv[j];
        }
        __syncthreads();
    }

    #pragma unroll
    for (int i = 0; i < 4; ++i) {
        const int r = bm + (ty << 2) + i;
        #pragma unroll
        for (int j = 0; j < 4; ++j) {
            const int c = bn + (tx << 2) + j;
            float val = acc[i][j] + bias[c];
            if (act == 1) {
                // exact GELU: x * 0.5 * (1 + erf(x/sqrt(2)))
                val = 0.5f * val * (1.0f + erff(val * 0.70710678118654752f));
            }
            C[(size_t)r * N + c] = val;
        }
    }
}

// ---------------------------------------------------------------------------
// Flash-style causal attention, fp32. One wave (64 lanes) per (query row, head).
// lane == head dim (D_HEAD == 64). Online softmax in registers.
// q/k/v layout: [T, C] with head h occupying columns h*64 .. h*64+63.
// ---------------------------------------------------------------------------
__launch_bounds__(64)
__global__ void attn_flash(const float* __restrict__ q, const float* __restrict__ k,
                           const float* __restrict__ v, float* __restrict__ o) {
    const int t = blockIdx.x;
    const int h = blockIdx.y;
    const int lane = threadIdx.x;

    const size_t base = (size_t)h * D_HEAD + lane;
    const float qv = q[(size_t)t * C_DIM + base];
    const float* kp = k + base;
    const float* vp = v + base;

    float m = -1e30f;
    float l = 0.0f;
    float acc = 0.0f;
    const float scale = 0.125f;  // 1/sqrt(64)

    for (int s = 0; s <= t; ++s) {
        float prod = qv * kp[(size_t)s * C_DIM];
        #pragma unroll
        for (int off = 32; off; off >>= 1)
            prod += __shfl_xor(prod, off);
        const float score = prod * scale;

        const float mn = fmaxf(m, score);
        const float corr = __expf(m - mn);      // first iter: exp(-huge) = 0
        const float p = __expf(score - mn);
        l = l * corr + p;
        acc = acc * corr + p * vp[(size_t)s * C_DIM];
        m = mn;
    }

    o[(size_t)t * C_DIM + base] = acc / l;
}

// ---------------------------------------------------------------------------
// Fused residual add + LayerNorm over C=768. One block (256 threads) per row.
// out = (a+b - mu) * rsqrt(var + eps) * g + beta
// ---------------------------------------------------------------------------
__launch_bounds__(256)
__global__ void add_ln(const float* __restrict__ a, const float* __restrict__ b,
                       const float* __restrict__ g, const float* __restrict__ beta,
                       float* __restrict__ out) {
    const int row = blockIdx.x;
    const int tid = threadIdx.x;
    const size_t rb = (size_t)row * C_DIM;

    float x[3];
    #pragma unroll
    for (int i = 0; i < 3; ++i) {
        const int c = tid + 256 * i;
        x[i] = a[rb + c] + b[rb + c];
    }

    float s = x[0] + x[1] + x[2];
    float s2 = x[0] * x[0] + x[1] * x[1] + x[2] * x[2];

    // wave reduce
    #pragma unroll
    for (int off = 32; off; off >>= 1) {
        s  += __shfl_xor(s, off);
        s2 += __shfl_xor(s2, off);
    }

    __shared__ float red[10];
    const int wave = tid >> 6;
    const int lane = tid & 63;
    if (lane == 0) { red[wave] = s; red[4 + wave] = s2; }
    __syncthreads();
    if (tid == 0) {
        const float ts  = red[0] + red[1] + red[2] + red[3];
        const float ts2 = red[4] + red[5] + red[6] + red[7];
        const float mu = ts * (1.0f / C_DIM);
        const float var = ts2 * (1.0f / C_DIM) - mu * mu;
        red[8] = mu;
        red[9] = rsqrtf(var + EPS);
    }
    __syncthreads();
    const float mu = red[8];
    const float rstd = red[9];

    #pragma unroll
    for (int i = 0; i < 3; ++i) {
        const int c = tid + 256 * i;
        out[rb + c] = (x[i] - mu) * rstd * g[c] + beta[c];
    }
}

// ---------------------------------------------------------------------------
extern "C" void kernel_launch(void* const* d_in, const int* in_sizes, int n_in,
                              void* d_out, int out_size, void* d_ws, size_t ws_size,
                              hipStream_t stream) {
    const float* x     = (const float*)d_in[0];
    const float* Wq    = (const float*)d_in[1];
    const float* bq    = (const float*)d_in[2];
    const float* Wk    = (const float*)d_in[3];
    const float* bk    = (const float*)d_in[4];
    const float* Wv    = (const float*)d_in[5];
    const float* bv    = (const float*)d_in[6];
    const float* Wo    = (const float*)d_in[7];
    const float* bo    = (const float*)d_in[8];
    const float* ln1_g = (const float*)d_in[9];
    const float* ln1_b = (const float*)d_in[10];
    const float* W1    = (const float*)d_in[11];
    const float* b1    = (const float*)d_in[12];
    const float* W2    = (const float*)d_in[13];
    const float* b2    = (const float*)d_in[14];
    const float* ln2_g = (const float*)d_in[15];
    const float* ln2_b = (const float*)d_in[16];

    float* out = (float*)d_out;

    const size_t TC = (size_t)T_SEQ * C_DIM;       // 3,145,728
    float* ws   = (float*)d_ws;
    float* qbuf = ws;                               // [T, C]
    float* kbuf = ws + TC;                          // [T, C]
    float* vbuf = ws + 2 * TC;                      // [T, C]
    float* obuf = ws + 3 * TC;                      // [T, C] attention output (heads concat)
    float* mid  = ws + 4 * TC;                      // [T, F] MLP hidden
    float* proj = qbuf;                             // reuse: attn out-projection
    float* hbuf = kbuf;                             // reuse: post-LN1 hidden
    float* mlpo = vbuf;                             // reuse: MLP output

    const dim3 blk256(256);

    // QKV projections
    {
        dim3 grid(C_DIM / BN, T_SEQ / BM);
        gemm_bias_act<<<grid, blk256, 0, stream>>>(x, Wq, bq, qbuf, T_SEQ, C_DIM, C_DIM, 0);
        gemm_bias_act<<<grid, blk256, 0, stream>>>(x, Wk, bk, kbuf, T_SEQ, C_DIM, C_DIM, 0);
        gemm_bias_act<<<grid, blk256, 0, stream>>>(x, Wv, bv, vbuf, T_SEQ, C_DIM, C_DIM, 0);
    }

    // causal attention
    {
        dim3 grid(T_SEQ, N_HEADS);
        attn_flash<<<grid, dim3(64), 0, stream>>>(qbuf, kbuf, vbuf, obuf);
    }

    // output projection (into qbuf, q is dead)
    {
        dim3 grid(C_DIM / BN, T_SEQ / BM);
        gemm_bias_act<<<grid, blk256, 0, stream>>>(obuf, Wo, bo, proj, T_SEQ, C_DIM, C_DIM, 0);
    }

    // h = LN(x + attn_proj)   (into kbuf, k is dead)
    add_ln<<<dim3(T_SEQ), blk256, 0, stream>>>(x, proj, ln1_g, ln1_b, hbuf);

    // MLP: mid = gelu(h @ W1 + b1)
    {
        dim3 grid(F_DIM / BN, T_SEQ / BM);
        gemm_bias_act<<<grid, blk256, 0, stream>>>(hbuf, W1, b1, mid, T_SEQ, F_DIM, C_DIM, 1);
    }
    // mlp_out = mid @ W2 + b2  (into vbuf, v is dead)
    {
        dim3 grid(C_DIM / BN, T_SEQ / BM);
        gemm_bias_act<<<grid, blk256, 0, stream>>>(mid, W2, b2, mlpo, T_SEQ, C_DIM, F_DIM, 0);
    }

    // y = LN(h + mlp_out)
    add_ln<<<dim3(T_SEQ), blk256, 0, stream>>>(hbuf, mlpo, ln2_g, ln2_b, out);
}

// Round 2
// 1157.725 us; speedup vs baseline: 6.8967x; 6.8967x over previous
//
#include <hip/hip_runtime.h>
#include <hip/hip_bf16.h>
#include <math.h>

// Problem constants
#define T_SEQ 4096
#define C_DIM 768
#define N_HEADS 12
#define D_HEAD 64
#define F_DIM 3072   // 4*C
#define EPS 1e-5f

typedef __attribute__((ext_vector_type(8))) short short8;
typedef __attribute__((ext_vector_type(4))) float f32x4;

// ---------------------------------------------------------------------------
// Tiled fp32 GEMM: out[M,N] = A[M,K] @ W[K,N] + bias[N].
// mode: 0 = f32 out, 1 = f32 out + exact GELU, 2 = bf16 out,
//       3 = bf16 out scaled by 0.125 (for Q), 4 = bf16 out TRANSPOSED (Vt[N][M])
// ---------------------------------------------------------------------------
#define BM 64
#define BN 64
#define BK 16

__launch_bounds__(256)
__global__ void gemm_bias_act(const float* __restrict__ A, const float* __restrict__ W,
                              const float* __restrict__ bias, void* __restrict__ outp,
                              int M, int N, int K, int mode) {
    __shared__ float As[BK][BM];   // A tile, transposed: As[k][m]
    __shared__ float Ws[BK][BN];   // W tile: Ws[k][n]

    const int tid = threadIdx.x;
    const int tx = tid & 15;
    const int ty = tid >> 4;
    const int bm = blockIdx.y * BM;
    const int bn = blockIdx.x * BN;

    float acc[4][4] = {};

    for (int k0 = 0; k0 < K; k0 += BK) {
        {
            const int row = tid >> 2;
            const int kg  = (tid & 3) << 2;
            const float4 a4 = *reinterpret_cast<const float4*>(
                &A[(size_t)(bm + row) * K + k0 + kg]);
            As[kg + 0][row] = a4.x;
            As[kg + 1][row] = a4.y;
            As[kg + 2][row] = a4.z;
            As[kg + 3][row] = a4.w;
        }
        {
            const int wr = tid >> 4;
            const int wc = (tid & 15) << 2;
            *reinterpret_cast<float4*>(&Ws[wr][wc]) =
                *reinterpret_cast<const float4*>(&W[(size_t)(k0 + wr) * N + bn + wc]);
        }
        __syncthreads();

        #pragma unroll
        for (int kk = 0; kk < BK; ++kk) {
            const float4 a4 = *reinterpret_cast<const float4*>(&As[kk][ty << 2]);
            const float4 b4 = *reinterpret_cast<const float4*>(&Ws[kk][tx << 2]);
            const float av[4] = {a4.x, a4.y, a4.z, a4.w};
            const float bv[4] = {b4.x, b4.y, b4.z, b4.w};
            #pragma unroll
            for (int i = 0; i < 4; ++i)
                #pragma unroll
                for (int j = 0; j < 4; ++j)
                    acc[i][j] += av[i] * bv[j];
        }
        __syncthreads();
    }

    #pragma unroll
    for (int i = 0; i < 4; ++i) {
        const int r = bm + (ty << 2) + i;
        #pragma unroll
        for (int j = 0; j < 4; ++j) {
            const int c = bn + (tx << 2) + j;
            float val = acc[i][j] + bias[c];
            if (mode == 1) {
                val = 0.5f * val * (1.0f + erff(val * 0.70710678118654752f));
            }
            if (mode <= 1) {
                ((float*)outp)[(size_t)r * N + c] = val;
            } else if (mode == 2) {
                ((__hip_bfloat16*)outp)[(size_t)r * N + c] = __float2bfloat16(val);
            } else if (mode == 3) {
                ((__hip_bfloat16*)outp)[(size_t)r * N + c] = __float2bfloat16(val * 0.125f);
            } else {  // mode 4: transposed bf16 (Vt[N][M])
                ((__hip_bfloat16*)outp)[(size_t)c * M + r] = __float2bfloat16(val);
            }
        }
    }
}

// ---------------------------------------------------------------------------
// Flash attention, bf16 MFMA. Block = 64 Q-rows x 1 head, 4 waves x 16 Q-rows.
// q: bf16 [T][C], pre-scaled by 1/8. k: bf16 [T][C]. vt: bf16 [C][T] (transposed).
// o: fp32 [T][C].
// MFMA 16x16x32 layouts (m89-verified D; standard A/B):
//   A: lane l holds A[l&15][ (l>>4)*8 + j ]   (8 bf16)
//   B: lane l holds B[(l>>4)*8 + j][ l&15 ]
//   D: lane l reg r holds D[(l>>4)*4 + r][ l&15 ]
// ---------------------------------------------------------------------------
#define QBLK 64
#define KBLK 64
#define LDP 72   // padded LDS row stride in bf16 elems (144 B -> 2-way conflicts only)

__launch_bounds__(256)
__global__ void attn_mfma(const __hip_bfloat16* __restrict__ q,
                          const __hip_bfloat16* __restrict__ k,
                          const __hip_bfloat16* __restrict__ vt,
                          float* __restrict__ o) {
    __shared__ __hip_bfloat16 Ks[KBLK][LDP];
    __shared__ __hip_bfloat16 Vts[D_HEAD][LDP];
    __shared__ __hip_bfloat16 Ps[4][16][LDP];

    const int tid  = threadIdx.x;
    const int wid  = tid >> 6;
    const int lane = tid & 63;
    const int lr   = lane & 15;   // frag row/col index
    const int lg   = lane >> 4;   // frag k-group / D-row group

    const int h  = blockIdx.y;
    const int q0 = T_SEQ - QBLK - blockIdx.x * QBLK;  // heavy blocks dispatch first
    const int qw = q0 + wid * 16;

    // Q fragments, held in registers for the whole K-loop
    short8 aq[2];
    #pragma unroll
    for (int kk = 0; kk < 2; ++kk)
        aq[kk] = *reinterpret_cast<const short8*>(
            &q[(size_t)(qw + lr) * C_DIM + h * D_HEAD + kk * 32 + lg * 8]);

    f32x4 o_acc[4];
    #pragma unroll
    for (int dc = 0; dc < 4; ++dc) o_acc[dc] = {0.f, 0.f, 0.f, 0.f};
    float m_run[4], l_run[4];
    #pragma unroll
    for (int r = 0; r < 4; ++r) { m_run[r] = -1e30f; l_run[r] = 0.f; }

    const int n_tiles = q0 / KBLK + 1;
    for (int t = 0; t < n_tiles; ++t) {
        const int s0 = t * KBLK;
        __syncthreads();   // previous iter's LDS reads complete before overwrite
        {
            const int row = tid >> 2;            // 0..63
            const int cb  = (tid & 3) * 16;      // 0,16,32,48
            const short8 k0 = *reinterpret_cast<const short8*>(
                &k[(size_t)(s0 + row) * C_DIM + h * D_HEAD + cb]);
            const short8 k1 = *reinterpret_cast<const short8*>(
                &k[(size_t)(s0 + row) * C_DIM + h * D_HEAD + cb + 8]);
            *reinterpret_cast<short8*>(&Ks[row][cb])     = k0;
            *reinterpret_cast<short8*>(&Ks[row][cb + 8]) = k1;
            const short8 v0 = *reinterpret_cast<const short8*>(
                &vt[(size_t)(h * D_HEAD + row) * T_SEQ + s0 + cb]);
            const short8 v1 = *reinterpret_cast<const short8*>(
                &vt[(size_t)(h * D_HEAD + row) * T_SEQ + s0 + cb + 8]);
            *reinterpret_cast<short8*>(&Vts[row][cb])     = v0;
            *reinterpret_cast<short8*>(&Vts[row][cb + 8]) = v1;
        }
        __syncthreads();

        // S = Q K^T (scale folded into Q)
        f32x4 s_acc[4];
        #pragma unroll
        for (int c = 0; c < 4; ++c) {
            s_acc[c] = {0.f, 0.f, 0.f, 0.f};
            #pragma unroll
            for (int kk = 0; kk < 2; ++kk) {
                const short8 bk8 = *reinterpret_cast<const short8*>(
                    &Ks[c * 16 + lr][kk * 32 + lg * 8]);
                s_acc[c] = __builtin_amdgcn_mfma_f32_16x16x32_bf16(aq[kk], bk8, s_acc[c], 0, 0, 0);
            }
        }

        // causal mask on the diagonal tile
        if (t == n_tiles - 1) {
            #pragma unroll
            for (int c = 0; c < 4; ++c)
                #pragma unroll
                for (int r = 0; r < 4; ++r) {
                    const int sn = c * 16 + lr;
                    const int qn = wid * 16 + lg * 4 + r;
                    if (sn > qn) s_acc[c][r] = -1e30f;
                }
        }

        // online softmax; lane owns rows lg*4+r, columns {c*16+lr}
        float rmax[4], rsum[4], p[4][4], corr[4];
        #pragma unroll
        for (int r = 0; r < 4; ++r)
            rmax[r] = fmaxf(fmaxf(s_acc[0][r], s_acc[1][r]),
                            fmaxf(s_acc[2][r], s_acc[3][r]));
        #pragma unroll
        for (int off = 1; off < 16; off <<= 1)
            #pragma unroll
            for (int r = 0; r < 4; ++r)
                rmax[r] = fmaxf(rmax[r], __shfl_xor(rmax[r], off));

        #pragma unroll
        for (int r = 0; r < 4; ++r) {
            const float mn = fmaxf(m_run[r], rmax[r]);
            corr[r] = __expf(m_run[r] - mn);
            m_run[r] = mn;
            rsum[r] = 0.f;
            #pragma unroll
            for (int c = 0; c < 4; ++c) {
                p[c][r] = __expf(s_acc[c][r] - mn);
                rsum[r] += p[c][r];
            }
        }
        #pragma unroll
        for (int off = 1; off < 16; off <<= 1)
            #pragma unroll
            for (int r = 0; r < 4; ++r)
                rsum[r] += __shfl_xor(rsum[r], off);
        #pragma unroll
        for (int r = 0; r < 4; ++r)
            l_run[r] = l_run[r] * corr[r] + rsum[r];
        #pragma unroll
        for (int dc = 0; dc < 4; ++dc)
            #pragma unroll
            for (int r = 0; r < 4; ++r)
                o_acc[dc][r] *= corr[r];

        // P -> per-wave LDS (reshape to A-fragment layout)
        #pragma unroll
        for (int c = 0; c < 4; ++c)
            #pragma unroll
            for (int r = 0; r < 4; ++r)
                Ps[wid][lg * 4 + r][c * 16 + lr] = __float2bfloat16(p[c][r]);
        // per-wave buffer: no __syncthreads needed (compiler inserts lgkmcnt)

        short8 ap[2];
        #pragma unroll
        for (int kk = 0; kk < 2; ++kk)
            ap[kk] = *reinterpret_cast<const short8*>(&Ps[wid][lr][kk * 32 + lg * 8]);
        #pragma unroll
        for (int dc = 0; dc < 4; ++dc)
            #pragma unroll
            for (int kk = 0; kk < 2; ++kk) {
                const short8 bv8 = *reinterpret_cast<const short8*>(
                    &Vts[dc * 16 + lr][kk * 32 + lg * 8]);
                o_acc[dc] = __builtin_amdgcn_mfma_f32_16x16x32_bf16(ap[kk], bv8, o_acc[dc], 0, 0, 0);
            }
    }

    #pragma unroll
    for (int dc = 0; dc < 4; ++dc)
        #pragma unroll
        for (int r = 0; r < 4; ++r)
            o[(size_t)(qw + lg * 4 + r) * C_DIM + h * D_HEAD + dc * 16 + lr] =
                o_acc[dc][r] / l_run[r];
}

// ---------------------------------------------------------------------------
// Fused residual add + LayerNorm over C=768. One block (256 threads) per row.
// ---------------------------------------------------------------------------
__launch_bounds__(256)
__global__ void add_ln(const float* __restrict__ a, const float* __restrict__ b,
                       const float* __restrict__ g, const float* __restrict__ beta,
                       float* __restrict__ out) {
    const int row = blockIdx.x;
    const int tid = threadIdx.x;
    const size_t rb = (size_t)row * C_DIM;

    float x[3];
    #pragma unroll
    for (int i = 0; i < 3; ++i) {
        const int c = tid + 256 * i;
        x[i] = a[rb + c] + b[rb + c];
    }

    float s = x[0] + x[1] + x[2];
    float s2 = x[0] * x[0] + x[1] * x[1] + x[2] * x[2];

    #pragma unroll
    for (int off = 32; off; off >>= 1) {
        s  += __shfl_xor(s, off);
        s2 += __shfl_xor(s2, off);
    }

    __shared__ float red[10];
    const int wave = tid >> 6;
    const int lane = tid & 63;
    if (lane == 0) { red[wave] = s; red[4 + wave] = s2; }
    __syncthreads();
    if (tid == 0) {
        const float ts  = red[0] + red[1] + red[2] + red[3];
        const float ts2 = red[4] + red[5] + red[6] + red[7];
        const float mu = ts * (1.0f / C_DIM);
        const float var = ts2 * (1.0f / C_DIM) - mu * mu;
        red[8] = mu;
        red[9] = rsqrtf(var + EPS);
    }
    __syncthreads();
    const float mu = red[8];
    const float rstd = red[9];

    #pragma unroll
    for (int i = 0; i < 3; ++i) {
        const int c = tid + 256 * i;
        out[rb + c] = (x[i] - mu) * rstd * g[c] + beta[c];
    }
}

// ---------------------------------------------------------------------------
extern "C" void kernel_launch(void* const* d_in, const int* in_sizes, int n_in,
                              void* d_out, int out_size, void* d_ws, size_t ws_size,
                              hipStream_t stream) {
    const float* x     = (const float*)d_in[0];
    const float* Wq    = (const float*)d_in[1];
    const float* bq    = (const float*)d_in[2];
    const float* Wk    = (const float*)d_in[3];
    const float* bk    = (const float*)d_in[4];
    const float* Wv    = (const float*)d_in[5];
    const float* bv    = (const float*)d_in[6];
    const float* Wo    = (const float*)d_in[7];
    const float* bo    = (const float*)d_in[8];
    const float* ln1_g = (const float*)d_in[9];
    const float* ln1_b = (const float*)d_in[10];
    const float* W1    = (const float*)d_in[11];
    const float* b1    = (const float*)d_in[12];
    const float* W2    = (const float*)d_in[13];
    const float* b2    = (const float*)d_in[14];
    const float* ln2_g = (const float*)d_in[15];
    const float* ln2_b = (const float*)d_in[16];

    float* out = (float*)d_out;

    const size_t TC = (size_t)T_SEQ * C_DIM;   // 3,145,728 elems
    char* wsb = (char*)d_ws;
    // byte layout (total ~94.4 MB)
    __hip_bfloat16* qbuf  = (__hip_bfloat16*)(wsb);                   // [T][C] bf16 (pre-scaled 1/8)
    __hip_bfloat16* kbuf  = (__hip_bfloat16*)(wsb + TC * 2);          // [T][C] bf16
    __hip_bfloat16* vtbuf = (__hip_bfloat16*)(wsb + TC * 4);          // [C][T] bf16 (transposed)
    float* obuf = (float*)(wsb + TC * 6);                             // [T][C] f32 attn out
    float* proj = (float*)(wsb + TC * 6 + TC * 4);                    // [T][C] f32
    float* hbuf = (float*)(wsb);                                      // [T][C] f32 (over dead q/k/vt)
    float* mid  = (float*)(wsb + TC * 6 + TC * 8);                    // [T][F] f32
    float* mlpo = obuf;                                               // reuse (obuf dead after proj)

    const dim3 blk256(256);

    // QKV projections (fp32 GEMM, bf16 out; Q pre-scaled by 1/8; V transposed)
    {
        dim3 grid(C_DIM / BN, T_SEQ / BM);
        gemm_bias_act<<<grid, blk256, 0, stream>>>(x, Wq, bq, qbuf,  T_SEQ, C_DIM, C_DIM, 3);
        gemm_bias_act<<<grid, blk256, 0, stream>>>(x, Wk, bk, kbuf,  T_SEQ, C_DIM, C_DIM, 2);
        gemm_bias_act<<<grid, blk256, 0, stream>>>(x, Wv, bv, vtbuf, T_SEQ, C_DIM, C_DIM, 4);
    }

    // flash attention (bf16 MFMA)
    {
        dim3 grid(T_SEQ / QBLK, N_HEADS);
        attn_mfma<<<grid, blk256, 0, stream>>>(qbuf, kbuf, vtbuf, obuf);
    }

    // output projection
    {
        dim3 grid(C_DIM / BN, T_SEQ / BM);
        gemm_bias_act<<<grid, blk256, 0, stream>>>(obuf, Wo, bo, proj, T_SEQ, C_DIM, C_DIM, 0);
    }

    // h = LN(x + attn_proj)
    add_ln<<<dim3(T_SEQ), blk256, 0, stream>>>(x, proj, ln1_g, ln1_b, hbuf);

    // MLP
    {
        dim3 grid(F_DIM / BN, T_SEQ / BM);
        gemm_bias_act<<<grid, blk256, 0, stream>>>(hbuf, W1, b1, mid, T_SEQ, F_DIM, C_DIM, 1);
    }
    {
        dim3 grid(C_DIM / BN, T_SEQ / BM);
        gemm_bias_act<<<grid, blk256, 0, stream>>>(mid, W2, b2, mlpo, T_SEQ, C_DIM, F_DIM, 0);
    }

    // y = LN(h + mlp_out)
    add_ln<<<dim3(T_SEQ), blk256, 0, stream>>>(hbuf, mlpo, ln2_g, ln2_b, out);
}

// Round 3
// 478.475 us; speedup vs baseline: 16.6875x; 2.4196x over previous
//
#include <hip/hip_runtime.h>
#include <hip/hip_bf16.h>
#include <math.h>

// Problem constants
#define T_SEQ 4096
#define C_DIM 768
#define N_HEADS 12
#define D_HEAD 64
#define F_DIM 3072   // 4*C
#define EPS 1e-5f

typedef __attribute__((ext_vector_type(8))) short short8;
typedef __attribute__((ext_vector_type(4))) float f32x4;

// async global->LDS, 16B per lane. LDS dest must be wave-uniform base (HW adds lane*16).
__device__ __forceinline__ void gload_lds16(const void* g, void* lds) {
    __builtin_amdgcn_global_load_lds(
        (const __attribute__((address_space(1))) unsigned int*)g,
        (__attribute__((address_space(3))) unsigned int*)lds, 16, 0, 0);
}

// ---------------------------------------------------------------------------
// Weight transpose + bf16 cast: W[K][N] f32 -> Wt[N][K] bf16. 64x64 tiles.
// ---------------------------------------------------------------------------
__launch_bounds__(256)
__global__ void transpose_w(const float* __restrict__ W, __hip_bfloat16* __restrict__ Wt,
                            int K, int N) {
    __shared__ float tile[64][65];
    const int k0 = blockIdx.x * 64;
    const int n0 = blockIdx.y * 64;
    const int tid = threadIdx.x;
    const int c = tid & 63;
    const int r0 = (tid >> 6) * 16;
    #pragma unroll
    for (int i = 0; i < 16; ++i)
        tile[r0 + i][c] = W[(size_t)(k0 + r0 + i) * N + n0 + c];
    __syncthreads();
    #pragma unroll
    for (int i = 0; i < 16; ++i)
        Wt[(size_t)(n0 + r0 + i) * K + k0 + c] = __float2bfloat16(tile[c][r0 + i]);
}

__launch_bounds__(256)
__global__ void concat_bias(const float* __restrict__ bq, const float* __restrict__ bk,
                            const float* __restrict__ bv, float* __restrict__ o) {
    const int i = blockIdx.x * 256 + threadIdx.x;
    if (i < C_DIM) {
        o[i] = bq[i];
        o[C_DIM + i] = bk[i];
        o[2 * C_DIM + i] = bv[i];
    }
}

__launch_bounds__(256)
__global__ void f32_to_bf16_vec(const float* __restrict__ in, __hip_bfloat16* __restrict__ out,
                                int n4) {
    const int i = blockIdx.x * 256 + threadIdx.x;
    if (i < n4) {
        const float4 v = *reinterpret_cast<const float4*>(&in[(size_t)i * 4]);
        ushort4 u;
        u.x = __bfloat16_as_ushort(__float2bfloat16(v.x));
        u.y = __bfloat16_as_ushort(__float2bfloat16(v.y));
        u.z = __bfloat16_as_ushort(__float2bfloat16(v.z));
        u.w = __bfloat16_as_ushort(__float2bfloat16(v.w));
        *reinterpret_cast<ushort4*>(&out[(size_t)i * 4]) = u;
    }
}

// ---------------------------------------------------------------------------
// bf16 MFMA GEMM, m97 structure: 128x128 tile, BK=64, 4 waves x (64x64 out),
// global_load_lds 16B staging, 2-barrier K-loop.
// A[M][K] bf16, Bt[N][K] bf16 (weights pre-transposed), bias[N] f32.
// MODE 0: f32 out + bias.
// MODE 1: bf16 out + bias + exact GELU.
// MODE 2: QKV split: cols [0,768) -> q bf16 *0.125; [768,1536) -> k bf16;
//         [1536,2304) -> vt bf16 transposed [C][T]. (block-uniform: 128 | 768)
// ---------------------------------------------------------------------------
#define GBM 128
#define GBN 128
#define GBK 64

template<int MODE>
__launch_bounds__(256)
__global__ void gemm_mfma(const __hip_bfloat16* __restrict__ A,
                          const __hip_bfloat16* __restrict__ Bt,
                          const float* __restrict__ bias,
                          float* __restrict__ outf,
                          __hip_bfloat16* __restrict__ outq,
                          __hip_bfloat16* __restrict__ outk,
                          __hip_bfloat16* __restrict__ outvt,
                          int M, int N, int K) {
    __shared__ __hip_bfloat16 As[GBM][GBK];   // 16 KB
    __shared__ __hip_bfloat16 Bs[GBN][GBK];   // 16 KB

    const int tid = threadIdx.x;
    const int l   = tid & 63;
    const int w   = tid >> 6;
    const int lr  = l & 15;
    const int lg  = l >> 4;
    const int wr  = w >> 1;
    const int wc  = w & 1;
    const int bm  = blockIdx.y * GBM;
    const int bn  = blockIdx.x * GBN;

    const int srow  = l >> 3;        // 0..7 row within 8-row chunk
    const int skoff = (l & 7) * 8;   // bf16 k-offset

    f32x4 acc[4][4];
    #pragma unroll
    for (int m = 0; m < 4; ++m)
        #pragma unroll
        for (int n = 0; n < 4; ++n)
            acc[m][n] = {0.f, 0.f, 0.f, 0.f};

    for (int k0 = 0; k0 < K; k0 += GBK) {
        if (k0) __syncthreads();   // prev compute done before overwrite
        #pragma unroll
        for (int i = 0; i < 4; ++i) {
            const int rb = (w * 4 + i) * 8;   // base row of this wave-issue (8 rows = 1 KB)
            gload_lds16(&A[(size_t)(bm + rb + srow) * K + k0 + skoff], &As[rb][0]);
            gload_lds16(&Bt[(size_t)(bn + rb + srow) * K + k0 + skoff], &Bs[rb][0]);
        }
        __syncthreads();           // vmcnt drain + barrier

        #pragma unroll
        for (int kk = 0; kk < 2; ++kk) {
            short8 af[4], bf[4];
            #pragma unroll
            for (int m = 0; m < 4; ++m)
                af[m] = *reinterpret_cast<const short8*>(&As[wr * 64 + m * 16 + lr][kk * 32 + lg * 8]);
            #pragma unroll
            for (int n = 0; n < 4; ++n)
                bf[n] = *reinterpret_cast<const short8*>(&Bs[wc * 64 + n * 16 + lr][kk * 32 + lg * 8]);
            #pragma unroll
            for (int m = 0; m < 4; ++m)
                #pragma unroll
                for (int n = 0; n < 4; ++n)
                    acc[m][n] = __builtin_amdgcn_mfma_f32_16x16x32_bf16(af[m], bf[n], acc[m][n], 0, 0, 0);
        }
    }

    // epilogue: D row = m*16 + lg*4 + rr (within wave tile), col = n*16 + lr
    #pragma unroll
    for (int m = 0; m < 4; ++m) {
        #pragma unroll
        for (int rr = 0; rr < 4; ++rr) {
            const int row = bm + wr * 64 + m * 16 + lg * 4 + rr;
            #pragma unroll
            for (int n = 0; n < 4; ++n) {
                const int col = bn + wc * 64 + n * 16 + lr;
                float v = acc[m][n][rr] + bias[col];
                if constexpr (MODE == 0) {
                    outf[(size_t)row * N + col] = v;
                } else if constexpr (MODE == 1) {
                    v = 0.5f * v * (1.0f + erff(v * 0.70710678118654752f));
                    outq[(size_t)row * N + col] = __float2bfloat16(v);
                } else {
                    if (col < C_DIM)
                        outq[(size_t)row * C_DIM + col] = __float2bfloat16(v * 0.125f);
                    else if (col < 2 * C_DIM)
                        outk[(size_t)row * C_DIM + (col - C_DIM)] = __float2bfloat16(v);
                    else
                        outvt[(size_t)(col - 2 * C_DIM) * T_SEQ + row] = __float2bfloat16(v);
                }
            }
        }
    }
}

// ---------------------------------------------------------------------------
// Flash attention, bf16 MFMA (validated R2). Output now bf16.
// ---------------------------------------------------------------------------
#define QBLK 64
#define KBLK 64
#define LDP 72

__launch_bounds__(256)
__global__ void attn_mfma(const __hip_bfloat16* __restrict__ q,
                          const __hip_bfloat16* __restrict__ k,
                          const __hip_bfloat16* __restrict__ vt,
                          __hip_bfloat16* __restrict__ o) {
    __shared__ __hip_bfloat16 Ks[KBLK][LDP];
    __shared__ __hip_bfloat16 Vts[D_HEAD][LDP];
    __shared__ __hip_bfloat16 Ps[4][16][LDP];

    const int tid  = threadIdx.x;
    const int wid  = tid >> 6;
    const int lane = tid & 63;
    const int lr   = lane & 15;
    const int lg   = lane >> 4;

    const int h  = blockIdx.y;
    const int q0 = T_SEQ - QBLK - blockIdx.x * QBLK;
    const int qw = q0 + wid * 16;

    short8 aq[2];
    #pragma unroll
    for (int kk = 0; kk < 2; ++kk)
        aq[kk] = *reinterpret_cast<const short8*>(
            &q[(size_t)(qw + lr) * C_DIM + h * D_HEAD + kk * 32 + lg * 8]);

    f32x4 o_acc[4];
    #pragma unroll
    for (int dc = 0; dc < 4; ++dc) o_acc[dc] = {0.f, 0.f, 0.f, 0.f};
    float m_run[4], l_run[4];
    #pragma unroll
    for (int r = 0; r < 4; ++r) { m_run[r] = -1e30f; l_run[r] = 0.f; }

    const int n_tiles = q0 / KBLK + 1;
    for (int t = 0; t < n_tiles; ++t) {
        const int s0 = t * KBLK;
        __syncthreads();
        {
            const int row = tid >> 2;
            const int cb  = (tid & 3) * 16;
            const short8 k0v = *reinterpret_cast<const short8*>(
                &k[(size_t)(s0 + row) * C_DIM + h * D_HEAD + cb]);
            const short8 k1v = *reinterpret_cast<const short8*>(
                &k[(size_t)(s0 + row) * C_DIM + h * D_HEAD + cb + 8]);
            *reinterpret_cast<short8*>(&Ks[row][cb])     = k0v;
            *reinterpret_cast<short8*>(&Ks[row][cb + 8]) = k1v;
            const short8 v0 = *reinterpret_cast<const short8*>(
                &vt[(size_t)(h * D_HEAD + row) * T_SEQ + s0 + cb]);
            const short8 v1 = *reinterpret_cast<const short8*>(
                &vt[(size_t)(h * D_HEAD + row) * T_SEQ + s0 + cb + 8]);
            *reinterpret_cast<short8*>(&Vts[row][cb])     = v0;
            *reinterpret_cast<short8*>(&Vts[row][cb + 8]) = v1;
        }
        __syncthreads();

        f32x4 s_acc[4];
        #pragma unroll
        for (int c = 0; c < 4; ++c) {
            s_acc[c] = {0.f, 0.f, 0.f, 0.f};
            #pragma unroll
            for (int kk = 0; kk < 2; ++kk) {
                const short8 bk8 = *reinterpret_cast<const short8*>(
                    &Ks[c * 16 + lr][kk * 32 + lg * 8]);
                s_acc[c] = __builtin_amdgcn_mfma_f32_16x16x32_bf16(aq[kk], bk8, s_acc[c], 0, 0, 0);
            }
        }

        if (t == n_tiles - 1) {
            #pragma unroll
            for (int c = 0; c < 4; ++c)
                #pragma unroll
                for (int r = 0; r < 4; ++r) {
                    const int sn = c * 16 + lr;
                    const int qn = wid * 16 + lg * 4 + r;
                    if (sn > qn) s_acc[c][r] = -1e30f;
                }
        }

        float rmax[4], rsum[4], p[4][4], corr[4];
        #pragma unroll
        for (int r = 0; r < 4; ++r)
            rmax[r] = fmaxf(fmaxf(s_acc[0][r], s_acc[1][r]),
                            fmaxf(s_acc[2][r], s_acc[3][r]));
        #pragma unroll
        for (int off = 1; off < 16; off <<= 1)
            #pragma unroll
            for (int r = 0; r < 4; ++r)
                rmax[r] = fmaxf(rmax[r], __shfl_xor(rmax[r], off));

        #pragma unroll
        for (int r = 0; r < 4; ++r) {
            const float mn = fmaxf(m_run[r], rmax[r]);
            corr[r] = __expf(m_run[r] - mn);
            m_run[r] = mn;
            rsum[r] = 0.f;
            #pragma unroll
            for (int c = 0; c < 4; ++c) {
                p[c][r] = __expf(s_acc[c][r] - mn);
                rsum[r] += p[c][r];
            }
        }
        #pragma unroll
        for (int off = 1; off < 16; off <<= 1)
            #pragma unroll
            for (int r = 0; r < 4; ++r)
                rsum[r] += __shfl_xor(rsum[r], off);
        #pragma unroll
        for (int r = 0; r < 4; ++r)
            l_run[r] = l_run[r] * corr[r] + rsum[r];
        #pragma unroll
        for (int dc = 0; dc < 4; ++dc)
            #pragma unroll
            for (int r = 0; r < 4; ++r)
                o_acc[dc][r] *= corr[r];

        #pragma unroll
        for (int c = 0; c < 4; ++c)
            #pragma unroll
            for (int r = 0; r < 4; ++r)
                Ps[wid][lg * 4 + r][c * 16 + lr] = __float2bfloat16(p[c][r]);

        short8 ap[2];
        #pragma unroll
        for (int kk = 0; kk < 2; ++kk)
            ap[kk] = *reinterpret_cast<const short8*>(&Ps[wid][lr][kk * 32 + lg * 8]);
        #pragma unroll
        for (int dc = 0; dc < 4; ++dc)
            #pragma unroll
            for (int kk = 0; kk < 2; ++kk) {
                const short8 bv8 = *reinterpret_cast<const short8*>(
                    &Vts[dc * 16 + lr][kk * 32 + lg * 8]);
                o_acc[dc] = __builtin_amdgcn_mfma_f32_16x16x32_bf16(ap[kk], bv8, o_acc[dc], 0, 0, 0);
            }
    }

    #pragma unroll
    for (int dc = 0; dc < 4; ++dc)
        #pragma unroll
        for (int r = 0; r < 4; ++r)
            o[(size_t)(qw + lg * 4 + r) * C_DIM + h * D_HEAD + dc * 16 + lr] =
                __float2bfloat16(o_acc[dc][r] / l_run[r]);
}

// ---------------------------------------------------------------------------
// Fused residual add + LayerNorm; optional bf16 secondary output.
// ---------------------------------------------------------------------------
template<bool WB16>
__launch_bounds__(256)
__global__ void add_ln(const float* __restrict__ a, const float* __restrict__ b,
                       const float* __restrict__ g, const float* __restrict__ beta,
                       float* __restrict__ outf, __hip_bfloat16* __restrict__ outb) {
    const int row = blockIdx.x;
    const int tid = threadIdx.x;
    const size_t rb = (size_t)row * C_DIM;

    float x[3];
    #pragma unroll
    for (int i = 0; i < 3; ++i) {
        const int c = tid + 256 * i;
        x[i] = a[rb + c] + b[rb + c];
    }

    float s = x[0] + x[1] + x[2];
    float s2 = x[0] * x[0] + x[1] * x[1] + x[2] * x[2];

    #pragma unroll
    for (int off = 32; off; off >>= 1) {
        s  += __shfl_xor(s, off);
        s2 += __shfl_xor(s2, off);
    }

    __shared__ float red[10];
    const int wave = tid >> 6;
    const int lane = tid & 63;
    if (lane == 0) { red[wave] = s; red[4 + wave] = s2; }
    __syncthreads();
    if (tid == 0) {
        const float ts  = red[0] + red[1] + red[2] + red[3];
        const float ts2 = red[4] + red[5] + red[6] + red[7];
        const float mu = ts * (1.0f / C_DIM);
        const float var = ts2 * (1.0f / C_DIM) - mu * mu;
        red[8] = mu;
        red[9] = rsqrtf(var + EPS);
    }
    __syncthreads();
    const float mu = red[8];
    const float rstd = red[9];

    #pragma unroll
    for (int i = 0; i < 3; ++i) {
        const int c = tid + 256 * i;
        const float v = (x[i] - mu) * rstd * g[c] + beta[c];
        outf[rb + c] = v;
        if constexpr (WB16) outb[rb + c] = __float2bfloat16(v);
    }
}

// ---------------------------------------------------------------------------
extern "C" void kernel_launch(void* const* d_in, const int* in_sizes, int n_in,
                              void* d_out, int out_size, void* d_ws, size_t ws_size,
                              hipStream_t stream) {
    const float* x     = (const float*)d_in[0];
    const float* Wq    = (const float*)d_in[1];
    const float* bq    = (const float*)d_in[2];
    const float* Wk    = (const float*)d_in[3];
    const float* bk    = (const float*)d_in[4];
    const float* Wv    = (const float*)d_in[5];
    const float* bv    = (const float*)d_in[6];
    const float* Wo    = (const float*)d_in[7];
    const float* bo    = (const float*)d_in[8];
    const float* ln1_g = (const float*)d_in[9];
    const float* ln1_b = (const float*)d_in[10];
    const float* W1    = (const float*)d_in[11];
    const float* b1    = (const float*)d_in[12];
    const float* W2    = (const float*)d_in[13];
    const float* b2    = (const float*)d_in[14];
    const float* ln2_g = (const float*)d_in[15];
    const float* ln2_b = (const float*)d_in[16];

    float* out = (float*)d_out;

    // --- workspace arena (bytes) ---
    char* wsb = (char*)d_ws;
    const size_t TCb16 = (size_t)T_SEQ * C_DIM * 2;          // 6,291,456
    // region A (25.2 MB): xb,q,k,vt  ->  later overlaid by mid [T][F] bf16
    __hip_bfloat16* xb  = (__hip_bfloat16*)(wsb);
    __hip_bfloat16* qb  = (__hip_bfloat16*)(wsb + TCb16);
    __hip_bfloat16* kb  = (__hip_bfloat16*)(wsb + 2 * TCb16);
    __hip_bfloat16* vtb = (__hip_bfloat16*)(wsb + 3 * TCb16);
    __hip_bfloat16* mid = (__hip_bfloat16*)(wsb);            // [T][F] bf16 overlays A
    // region B (12.6 MB): proj f32, later mlpo f32
    float* proj = (float*)(wsb + 4 * TCb16);
    float* mlpo = proj;
    // region C (6.3 MB): obuf bf16, later hb bf16
    __hip_bfloat16* obuf = (__hip_bfloat16*)(wsb + 4 * TCb16 + 12582912);
    __hip_bfloat16* hb   = obuf;
    // region D (12.6 MB): hbuf f32
    float* hbuf = (float*)(wsb + 4 * TCb16 + 12582912 + TCb16);
    // region E: transposed bf16 weights + concat bias
    char* we = wsb + 4 * TCb16 + 12582912 + TCb16 + 12582912;
    __hip_bfloat16* Wqkv_t = (__hip_bfloat16*)(we);                       // [2304][768]
    __hip_bfloat16* Wo_t   = (__hip_bfloat16*)(we + 3538944);             // [768][768]
    __hip_bfloat16* W1_t   = (__hip_bfloat16*)(we + 3538944 + 1179648);   // [3072][768]
    __hip_bfloat16* W2_t   = (__hip_bfloat16*)(we + 3538944 + 1179648 + 4718592); // [768][3072]
    float* bqkv            = (float*)(we + 3538944 + 1179648 + 2 * 4718592);

    const dim3 blk256(256);

    // --- weight prep (all independent) ---
    transpose_w<<<dim3(12, 12), blk256, 0, stream>>>(Wq, Wqkv_t,                   C_DIM, C_DIM);
    transpose_w<<<dim3(12, 12), blk256, 0, stream>>>(Wk, Wqkv_t + (size_t)C_DIM * C_DIM,     C_DIM, C_DIM);
    transpose_w<<<dim3(12, 12), blk256, 0, stream>>>(Wv, Wqkv_t + (size_t)2 * C_DIM * C_DIM, C_DIM, C_DIM);
    transpose_w<<<dim3(12, 12), blk256, 0, stream>>>(Wo, Wo_t, C_DIM, C_DIM);
    transpose_w<<<dim3(12, 48), blk256, 0, stream>>>(W1, W1_t, C_DIM, F_DIM);
    transpose_w<<<dim3(48, 12), blk256, 0, stream>>>(W2, W2_t, F_DIM, C_DIM);
    concat_bias<<<dim3(3), blk256, 0, stream>>>(bq, bk, bv, bqkv);
    f32_to_bf16_vec<<<dim3(3072), blk256, 0, stream>>>(x, xb, T_SEQ * C_DIM / 4);

    // --- fused QKV GEMM: [T,768] @ [768,2304], epilogue splits q/k/vt ---
    gemm_mfma<2><<<dim3(3 * C_DIM / GBN, T_SEQ / GBM), blk256, 0, stream>>>(
        xb, Wqkv_t, bqkv, nullptr, qb, kb, vtb, T_SEQ, 3 * C_DIM, C_DIM);

    // --- flash attention ---
    attn_mfma<<<dim3(T_SEQ / QBLK, N_HEADS), blk256, 0, stream>>>(qb, kb, vtb, obuf);

    // --- output projection -> f32 proj ---
    gemm_mfma<0><<<dim3(C_DIM / GBN, T_SEQ / GBM), blk256, 0, stream>>>(
        obuf, Wo_t, bo, proj, nullptr, nullptr, nullptr, T_SEQ, C_DIM, C_DIM);

    // --- h = LN(x + proj): f32 + bf16 ---
    add_ln<true><<<dim3(T_SEQ), blk256, 0, stream>>>(x, proj, ln1_g, ln1_b, hbuf, hb);

    // --- MLP1: gelu(h @ W1 + b1) -> bf16 mid ---
    gemm_mfma<1><<<dim3(F_DIM / GBN, T_SEQ / GBM), blk256, 0, stream>>>(
        hb, W1_t, b1, nullptr, mid, nullptr, nullptr, T_SEQ, F_DIM, C_DIM);

    // --- MLP2: mid @ W2 + b2 -> f32 mlpo ---
    gemm_mfma<0><<<dim3(C_DIM / GBN, T_SEQ / GBM), blk256, 0, stream>>>(
        mid, W2_t, b2, mlpo, nullptr, nullptr, nullptr, T_SEQ, C_DIM, F_DIM);

    // --- y = LN(h + mlpo) ---
    add_ln<false><<<dim3(T_SEQ), blk256, 0, stream>>>(hbuf, mlpo, ln2_g, ln2_b, out, nullptr);
}

// Round 4
// 434.585 us; speedup vs baseline: 18.3728x; 1.1010x over previous
//
#include <hip/hip_runtime.h>
#include <hip/hip_bf16.h>
#include <math.h>

// Problem constants
#define T_SEQ 4096
#define C_DIM 768
#define N_HEADS 12
#define D_HEAD 64
#define F_DIM 3072   // 4*C
#define EPS 1e-5f
#define QSCALE 0.18033688011112042f   // (1/8) * log2(e): softmax done in base-2

typedef __attribute__((ext_vector_type(8))) short short8;
typedef __attribute__((ext_vector_type(4))) float f32x4;

// async global->LDS, 16B per lane. LDS dest must be wave-uniform base (HW adds lane*16).
__device__ __forceinline__ void gload_lds16(const void* g, void* lds) {
    __builtin_amdgcn_global_load_lds(
        (const __attribute__((address_space(1))) unsigned int*)g,
        (__attribute__((address_space(3))) unsigned int*)lds, 16, 0, 0);
}

// ---------------------------------------------------------------------------
// Weight transpose + bf16 cast: W[K][N] f32 -> Wt[N][K] bf16. 64x64 tiles.
// ---------------------------------------------------------------------------
__launch_bounds__(256)
__global__ void transpose_w(const float* __restrict__ W, __hip_bfloat16* __restrict__ Wt,
                            int K, int N) {
    __shared__ float tile[64][65];
    const int k0 = blockIdx.x * 64;
    const int n0 = blockIdx.y * 64;
    const int tid = threadIdx.x;
    const int c = tid & 63;
    const int r0 = (tid >> 6) * 16;
    #pragma unroll
    for (int i = 0; i < 16; ++i)
        tile[r0 + i][c] = W[(size_t)(k0 + r0 + i) * N + n0 + c];
    __syncthreads();
    #pragma unroll
    for (int i = 0; i < 16; ++i)
        Wt[(size_t)(n0 + r0 + i) * K + k0 + c] = __float2bfloat16(tile[c][r0 + i]);
}

__launch_bounds__(256)
__global__ void concat_bias(const float* __restrict__ bq, const float* __restrict__ bk,
                            const float* __restrict__ bv, float* __restrict__ o) {
    const int i = blockIdx.x * 256 + threadIdx.x;
    if (i < C_DIM) {
        o[i] = bq[i];
        o[C_DIM + i] = bk[i];
        o[2 * C_DIM + i] = bv[i];
    }
}

__launch_bounds__(256)
__global__ void f32_to_bf16_vec(const float* __restrict__ in, __hip_bfloat16* __restrict__ out,
                                int n4) {
    const int i = blockIdx.x * 256 + threadIdx.x;
    if (i < n4) {
        const float4 v = *reinterpret_cast<const float4*>(&in[(size_t)i * 4]);
        ushort4 u;
        u.x = __bfloat16_as_ushort(__float2bfloat16(v.x));
        u.y = __bfloat16_as_ushort(__float2bfloat16(v.y));
        u.z = __bfloat16_as_ushort(__float2bfloat16(v.z));
        u.w = __bfloat16_as_ushort(__float2bfloat16(v.w));
        *reinterpret_cast<ushort4*>(&out[(size_t)i * 4]) = u;
    }
}

// ---------------------------------------------------------------------------
// bf16 MFMA GEMM, m97 structure: 128x128 tile, BK=64, 4 waves x (64x64 out),
// global_load_lds 16B staging, 2-barrier K-loop.
// MODE 0: f32 out + bias. MODE 1: bf16 out + bias + exact GELU.
// MODE 2: QKV split: q (bf16, * QSCALE) / k (bf16) / vt (bf16 transposed).
// ---------------------------------------------------------------------------
#define GBM 128
#define GBN 128
#define GBK 64

template<int MODE>
__launch_bounds__(256)
__global__ void gemm_mfma(const __hip_bfloat16* __restrict__ A,
                          const __hip_bfloat16* __restrict__ Bt,
                          const float* __restrict__ bias,
                          float* __restrict__ outf,
                          __hip_bfloat16* __restrict__ outq,
                          __hip_bfloat16* __restrict__ outk,
                          __hip_bfloat16* __restrict__ outvt,
                          int M, int N, int K) {
    __shared__ __hip_bfloat16 As[GBM][GBK];   // 16 KB
    __shared__ __hip_bfloat16 Bs[GBN][GBK];   // 16 KB

    const int tid = threadIdx.x;
    const int l   = tid & 63;
    const int w   = tid >> 6;
    const int lr  = l & 15;
    const int lg  = l >> 4;
    const int wr  = w >> 1;
    const int wc  = w & 1;
    const int bm  = blockIdx.y * GBM;
    const int bn  = blockIdx.x * GBN;

    const int srow  = l >> 3;        // 0..7 row within 8-row chunk
    const int skoff = (l & 7) * 8;   // bf16 k-offset

    f32x4 acc[4][4];
    #pragma unroll
    for (int m = 0; m < 4; ++m)
        #pragma unroll
        for (int n = 0; n < 4; ++n)
            acc[m][n] = {0.f, 0.f, 0.f, 0.f};

    for (int k0 = 0; k0 < K; k0 += GBK) {
        if (k0) __syncthreads();
        #pragma unroll
        for (int i = 0; i < 4; ++i) {
            const int rb = (w * 4 + i) * 8;
            gload_lds16(&A[(size_t)(bm + rb + srow) * K + k0 + skoff], &As[rb][0]);
            gload_lds16(&Bt[(size_t)(bn + rb + srow) * K + k0 + skoff], &Bs[rb][0]);
        }
        __syncthreads();

        #pragma unroll
        for (int kk = 0; kk < 2; ++kk) {
            short8 af[4], bf[4];
            #pragma unroll
            for (int m = 0; m < 4; ++m)
                af[m] = *reinterpret_cast<const short8*>(&As[wr * 64 + m * 16 + lr][kk * 32 + lg * 8]);
            #pragma unroll
            for (int n = 0; n < 4; ++n)
                bf[n] = *reinterpret_cast<const short8*>(&Bs[wc * 64 + n * 16 + lr][kk * 32 + lg * 8]);
            #pragma unroll
            for (int m = 0; m < 4; ++m)
                #pragma unroll
                for (int n = 0; n < 4; ++n)
                    acc[m][n] = __builtin_amdgcn_mfma_f32_16x16x32_bf16(af[m], bf[n], acc[m][n], 0, 0, 0);
        }
    }

    #pragma unroll
    for (int m = 0; m < 4; ++m) {
        #pragma unroll
        for (int rr = 0; rr < 4; ++rr) {
            const int row = bm + wr * 64 + m * 16 + lg * 4 + rr;
            #pragma unroll
            for (int n = 0; n < 4; ++n) {
                const int col = bn + wc * 64 + n * 16 + lr;
                float v = acc[m][n][rr] + bias[col];
                if constexpr (MODE == 0) {
                    outf[(size_t)row * N + col] = v;
                } else if constexpr (MODE == 1) {
                    v = 0.5f * v * (1.0f + erff(v * 0.70710678118654752f));
                    outq[(size_t)row * N + col] = __float2bfloat16(v);
                } else {
                    if (col < C_DIM)
                        outq[(size_t)row * C_DIM + col] = __float2bfloat16(v * QSCALE);
                    else if (col < 2 * C_DIM)
                        outk[(size_t)row * C_DIM + (col - C_DIM)] = __float2bfloat16(v);
                    else
                        outvt[(size_t)(col - 2 * C_DIM) * T_SEQ + row] = __float2bfloat16(v);
                }
            }
        }
    }
}

// ---------------------------------------------------------------------------
// Flash attention, bf16 MFMA. QBLK=64 (4 waves x 16 q-rows), KVB=128.
// Logical layout identical to the R3-verified kernel; physical LDS addressing
// is XOR-swizzled (T2) and staged via global_load_lds with inverse-swizzled
// per-lane source (rule #21 pattern). Softmax in base-2 (scale folded into Q).
//   Ks  [128][64]  : slot(16B) ^= row&7
//   Vts [64][128]  : slot ^= row&15
//   Ps  [4][16][128]: slot ^= row (q-row 0..15)
// ---------------------------------------------------------------------------
#define QBLK 64
#define KVB 128

__launch_bounds__(256)
__global__ void attn_mfma(const __hip_bfloat16* __restrict__ q,
                          const __hip_bfloat16* __restrict__ k,
                          const __hip_bfloat16* __restrict__ vt,
                          __hip_bfloat16* __restrict__ o) {
    __shared__ __hip_bfloat16 Ks[KVB][64];
    __shared__ __hip_bfloat16 Vts[D_HEAD][KVB];
    __shared__ __hip_bfloat16 Ps[4][16][KVB];

    const int tid  = threadIdx.x;
    const int wid  = tid >> 6;
    const int lane = tid & 63;
    const int lr   = lane & 15;
    const int lg   = lane >> 4;

    const int h  = blockIdx.y;
    const int q0 = T_SEQ - QBLK - blockIdx.x * QBLK;  // heavy blocks dispatch first
    const int qw = q0 + wid * 16;

    // K-stage source col offset (elems): inverse swizzle, lane-only constant
    const int ksrc = 8 * ((lane & 7) ^ (lane >> 3));
    const int kr   = lane >> 3;   // row within 8-row chunk
    const int vr   = lane >> 4;   // row within 4-row chunk
    const int vs   = lane & 15;   // V slot

    // Q fragments in registers (already scaled by QSCALE in the QKV epilogue)
    short8 aq[2];
    #pragma unroll
    for (int kk = 0; kk < 2; ++kk)
        aq[kk] = *reinterpret_cast<const short8*>(
            &q[(size_t)(qw + lr) * C_DIM + h * D_HEAD + kk * 32 + lg * 8]);

    f32x4 o_acc[4];
    #pragma unroll
    for (int dc = 0; dc < 4; ++dc) o_acc[dc] = {0.f, 0.f, 0.f, 0.f};
    float m_run[4], l_run[4];
    #pragma unroll
    for (int r = 0; r < 4; ++r) { m_run[r] = -1e30f; l_run[r] = 0.f; }

    const int n_tiles = (q0 + QBLK + KVB - 1) / KVB;
    for (int t = 0; t < n_tiles; ++t) {
        const int s0 = t * KVB;
        __syncthreads();   // prev tile's LDS reads complete before overwrite
        // --- stage K tile: wave w covers rows [w*32, w*32+32), 4 x 1KB issues ---
        #pragma unroll
        for (int i = 0; i < 4; ++i) {
            const int rb = wid * 32 + i * 8;
            gload_lds16(&k[(size_t)(s0 + rb + kr) * C_DIM + h * D_HEAD + ksrc], &Ks[rb][0]);
        }
        // --- stage V tile: wave w covers rows [w*16, w*16+16), 4 x 1KB issues ---
        #pragma unroll
        for (int i = 0; i < 4; ++i) {
            const int vb = wid * 16 + i * 4;
            const int vsrc = 8 * (vs ^ (i * 4 + vr));
            gload_lds16(&vt[(size_t)(h * D_HEAD + vb + vr) * T_SEQ + s0 + vsrc], &Vts[vb][0]);
        }
        __syncthreads();   // vmcnt drain + barrier

        // --- S = Q K^T (base-2-scaled), 8 column tiles ---
        f32x4 s_acc[8];
        #pragma unroll
        for (int c = 0; c < 8; ++c) {
            s_acc[c] = {0.f, 0.f, 0.f, 0.f};
            #pragma unroll
            for (int kk = 0; kk < 2; ++kk) {
                const short8 bk8 = *reinterpret_cast<const short8*>(
                    &Ks[c * 16 + lr][8 * ((4 * kk + lg) ^ (lr & 7))]);
                s_acc[c] = __builtin_amdgcn_mfma_f32_16x16x32_bf16(aq[kk], bk8, s_acc[c], 0, 0, 0);
            }
        }

        // causal mask (last tile only; uses global indices)
        if (t == n_tiles - 1) {
            #pragma unroll
            for (int c = 0; c < 8; ++c)
                #pragma unroll
                for (int r = 0; r < 4; ++r) {
                    const int sg = s0 + c * 16 + lr;
                    const int qg = qw + lg * 4 + r;
                    if (sg > qg) s_acc[c][r] = -1e30f;
                }
        }

        // --- online softmax (base-2); lane owns rows lg*4+r, cols {c*16+lr} ---
        float rmax[4];
        #pragma unroll
        for (int r = 0; r < 4; ++r) {
            float m0 = fmaxf(fmaxf(s_acc[0][r], s_acc[1][r]), fmaxf(s_acc[2][r], s_acc[3][r]));
            float m1 = fmaxf(fmaxf(s_acc[4][r], s_acc[5][r]), fmaxf(s_acc[6][r], s_acc[7][r]));
            rmax[r] = fmaxf(m0, m1);
        }
        #pragma unroll
        for (int off = 1; off < 16; off <<= 1)
            #pragma unroll
            for (int r = 0; r < 4; ++r)
                rmax[r] = fmaxf(rmax[r], __shfl_xor(rmax[r], off));

        float corr[4], rsum[4];
        #pragma unroll
        for (int r = 0; r < 4; ++r) {
            const float mn = fmaxf(m_run[r], rmax[r]);
            corr[r] = __builtin_amdgcn_exp2f(m_run[r] - mn);
            m_run[r] = mn;
            rsum[r] = 0.f;
        }
        // exp2 + P write (swizzled) + row-sum accumulate
        #pragma unroll
        for (int c = 0; c < 8; ++c)
            #pragma unroll
            for (int r = 0; r < 4; ++r) {
                const float pv = __builtin_amdgcn_exp2f(s_acc[c][r] - m_run[r]);
                rsum[r] += pv;
                const int qrow = lg * 4 + r;
                const int slot = (2 * c + (lr >> 3)) ^ qrow;
                Ps[wid][qrow][slot * 8 + (lr & 7)] = __float2bfloat16(pv);
            }
        #pragma unroll
        for (int off = 1; off < 16; off <<= 1)
            #pragma unroll
            for (int r = 0; r < 4; ++r)
                rsum[r] += __shfl_xor(rsum[r], off);
        #pragma unroll
        for (int r = 0; r < 4; ++r)
            l_run[r] = l_run[r] * corr[r] + rsum[r];
        #pragma unroll
        for (int dc = 0; dc < 4; ++dc)
            #pragma unroll
            for (int r = 0; r < 4; ++r)
                o_acc[dc][r] *= corr[r];

        // --- PV: O += P V ---
        short8 ap[4];
        #pragma unroll
        for (int kk = 0; kk < 4; ++kk)
            ap[kk] = *reinterpret_cast<const short8*>(
                &Ps[wid][lr][8 * ((4 * kk + lg) ^ lr)]);
        #pragma unroll
        for (int dc = 0; dc < 4; ++dc)
            #pragma unroll
            for (int kk = 0; kk < 4; ++kk) {
                const short8 bv8 = *reinterpret_cast<const short8*>(
                    &Vts[dc * 16 + lr][8 * ((4 * kk + lg) ^ lr)]);
                o_acc[dc] = __builtin_amdgcn_mfma_f32_16x16x32_bf16(ap[kk], bv8, o_acc[dc], 0, 0, 0);
            }
    }

    #pragma unroll
    for (int dc = 0; dc < 4; ++dc)
        #pragma unroll
        for (int r = 0; r < 4; ++r)
            o[(size_t)(qw + lg * 4 + r) * C_DIM + h * D_HEAD + dc * 16 + lr] =
                __float2bfloat16(o_acc[dc][r] / l_run[r]);
}

// ---------------------------------------------------------------------------
// Fused residual add + LayerNorm; optional bf16 secondary output.
// ---------------------------------------------------------------------------
template<bool WB16>
__launch_bounds__(256)
__global__ void add_ln(const float* __restrict__ a, const float* __restrict__ b,
                       const float* __restrict__ g, const float* __restrict__ beta,
                       float* __restrict__ outf, __hip_bfloat16* __restrict__ outb) {
    const int row = blockIdx.x;
    const int tid = threadIdx.x;
    const size_t rb = (size_t)row * C_DIM;

    float x[3];
    #pragma unroll
    for (int i = 0; i < 3; ++i) {
        const int c = tid + 256 * i;
        x[i] = a[rb + c] + b[rb + c];
    }

    float s = x[0] + x[1] + x[2];
    float s2 = x[0] * x[0] + x[1] * x[1] + x[2] * x[2];

    #pragma unroll
    for (int off = 32; off; off >>= 1) {
        s  += __shfl_xor(s, off);
        s2 += __shfl_xor(s2, off);
    }

    __shared__ float red[10];
    const int wave = tid >> 6;
    const int lane = tid & 63;
    if (lane == 0) { red[wave] = s; red[4 + wave] = s2; }
    __syncthreads();
    if (tid == 0) {
        const float ts  = red[0] + red[1] + red[2] + red[3];
        const float ts2 = red[4] + red[5] + red[6] + red[7];
        const float mu = ts * (1.0f / C_DIM);
        const float var = ts2 * (1.0f / C_DIM) - mu * mu;
        red[8] = mu;
        red[9] = rsqrtf(var + EPS);
    }
    __syncthreads();
    const float mu = red[8];
    const float rstd = red[9];

    #pragma unroll
    for (int i = 0; i < 3; ++i) {
        const int c = tid + 256 * i;
        const float v = (x[i] - mu) * rstd * g[c] + beta[c];
        outf[rb + c] = v;
        if constexpr (WB16) outb[rb + c] = __float2bfloat16(v);
    }
}

// ---------------------------------------------------------------------------
extern "C" void kernel_launch(void* const* d_in, const int* in_sizes, int n_in,
                              void* d_out, int out_size, void* d_ws, size_t ws_size,
                              hipStream_t stream) {
    const float* x     = (const float*)d_in[0];
    const float* Wq    = (const float*)d_in[1];
    const float* bq    = (const float*)d_in[2];
    const float* Wk    = (const float*)d_in[3];
    const float* bk    = (const float*)d_in[4];
    const float* Wv    = (const float*)d_in[5];
    const float* bv    = (const float*)d_in[6];
    const float* Wo    = (const float*)d_in[7];
    const float* bo    = (const float*)d_in[8];
    const float* ln1_g = (const float*)d_in[9];
    const float* ln1_b = (const float*)d_in[10];
    const float* W1    = (const float*)d_in[11];
    const float* b1    = (const float*)d_in[12];
    const float* W2    = (const float*)d_in[13];
    const float* b2    = (const float*)d_in[14];
    const float* ln2_g = (const float*)d_in[15];
    const float* ln2_b = (const float*)d_in[16];

    float* out = (float*)d_out;

    // --- workspace arena (bytes) ---
    char* wsb = (char*)d_ws;
    const size_t TCb16 = (size_t)T_SEQ * C_DIM * 2;          // 6,291,456
    __hip_bfloat16* xb  = (__hip_bfloat16*)(wsb);
    __hip_bfloat16* qb  = (__hip_bfloat16*)(wsb + TCb16);
    __hip_bfloat16* kb  = (__hip_bfloat16*)(wsb + 2 * TCb16);
    __hip_bfloat16* vtb = (__hip_bfloat16*)(wsb + 3 * TCb16);
    __hip_bfloat16* mid = (__hip_bfloat16*)(wsb);            // [T][F] bf16 overlays A
    float* proj = (float*)(wsb + 4 * TCb16);
    float* mlpo = proj;
    __hip_bfloat16* obuf = (__hip_bfloat16*)(wsb + 4 * TCb16 + 12582912);
    __hip_bfloat16* hb   = obuf;
    float* hbuf = (float*)(wsb + 4 * TCb16 + 12582912 + TCb16);
    char* we = wsb + 4 * TCb16 + 12582912 + TCb16 + 12582912;
    __hip_bfloat16* Wqkv_t = (__hip_bfloat16*)(we);                       // [2304][768]
    __hip_bfloat16* Wo_t   = (__hip_bfloat16*)(we + 3538944);             // [768][768]
    __hip_bfloat16* W1_t   = (__hip_bfloat16*)(we + 3538944 + 1179648);   // [3072][768]
    __hip_bfloat16* W2_t   = (__hip_bfloat16*)(we + 3538944 + 1179648 + 4718592); // [768][3072]
    float* bqkv            = (float*)(we + 3538944 + 1179648 + 2 * 4718592);

    const dim3 blk256(256);

    // --- weight prep (all independent) ---
    transpose_w<<<dim3(12, 12), blk256, 0, stream>>>(Wq, Wqkv_t,                   C_DIM, C_DIM);
    transpose_w<<<dim3(12, 12), blk256, 0, stream>>>(Wk, Wqkv_t + (size_t)C_DIM * C_DIM,     C_DIM, C_DIM);
    transpose_w<<<dim3(12, 12), blk256, 0, stream>>>(Wv, Wqkv_t + (size_t)2 * C_DIM * C_DIM, C_DIM, C_DIM);
    transpose_w<<<dim3(12, 12), blk256, 0, stream>>>(Wo, Wo_t, C_DIM, C_DIM);
    transpose_w<<<dim3(12, 48), blk256, 0, stream>>>(W1, W1_t, C_DIM, F_DIM);
    transpose_w<<<dim3(48, 12), blk256, 0, stream>>>(W2, W2_t, F_DIM, C_DIM);
    concat_bias<<<dim3(3), blk256, 0, stream>>>(bq, bk, bv, bqkv);
    f32_to_bf16_vec<<<dim3(3072), blk256, 0, stream>>>(x, xb, T_SEQ * C_DIM / 4);

    // --- fused QKV GEMM: [T,768] @ [768,2304], epilogue splits q/k/vt ---
    gemm_mfma<2><<<dim3(3 * C_DIM / GBN, T_SEQ / GBM), blk256, 0, stream>>>(
        xb, Wqkv_t, bqkv, nullptr, qb, kb, vtb, T_SEQ, 3 * C_DIM, C_DIM);

    // --- flash attention ---
    attn_mfma<<<dim3(T_SEQ / QBLK, N_HEADS), blk256, 0, stream>>>(qb, kb, vtb, obuf);

    // --- output projection -> f32 proj ---
    gemm_mfma<0><<<dim3(C_DIM / GBN, T_SEQ / GBM), blk256, 0, stream>>>(
        obuf, Wo_t, bo, proj, nullptr, nullptr, nullptr, T_SEQ, C_DIM, C_DIM);

    // --- h = LN(x + proj): f32 + bf16 ---
    add_ln<true><<<dim3(T_SEQ), blk256, 0, stream>>>(x, proj, ln1_g, ln1_b, hbuf, hb);

    // --- MLP1: gelu(h @ W1 + b1) -> bf16 mid ---
    gemm_mfma<1><<<dim3(F_DIM / GBN, T_SEQ / GBM), blk256, 0, stream>>>(
        hb, W1_t, b1, nullptr, mid, nullptr, nullptr, T_SEQ, F_DIM, C_DIM);

    // --- MLP2: mid @ W2 + b2 -> f32 mlpo ---
    gemm_mfma<0><<<dim3(C_DIM / GBN, T_SEQ / GBM), blk256, 0, stream>>>(
        mid, W2_t, b2, mlpo, nullptr, nullptr, nullptr, T_SEQ, C_DIM, F_DIM);

    // --- y = LN(h + mlpo) ---
    add_ln<false><<<dim3(T_SEQ), blk256, 0, stream>>>(hbuf, mlpo, ln2_g, ln2_b, out, nullptr);
}

// Round 5
// 366.166 us; speedup vs baseline: 21.8057x; 1.1869x over previous
//
#include <hip/hip_runtime.h>
#include <hip/hip_bf16.h>
#include <math.h>

// Problem constants
#define T_SEQ 4096
#define C_DIM 768
#define N_HEADS 12
#define D_HEAD 64
#define F_DIM 3072   // 4*C
#define EPS 1e-5f
#define QSCALE 0.18033688011112042f   // (1/8) * log2(e): softmax done in base-2

typedef __attribute__((ext_vector_type(8))) short short8;
typedef __attribute__((ext_vector_type(4))) float f32x4;

// async global->LDS, 16B per lane. LDS dest must be wave-uniform base (HW adds lane*16).
__device__ __forceinline__ void gload_lds16(const void* g, void* lds) {
    __builtin_amdgcn_global_load_lds(
        (const __attribute__((address_space(1))) unsigned int*)g,
        (__attribute__((address_space(3))) unsigned int*)lds, 16, 0, 0);
}

// ---------------------------------------------------------------------------
// Weight transpose + bf16 cast: W[K][N] f32 -> Wt[N][K] bf16. 64x64 tiles.
// ---------------------------------------------------------------------------
__launch_bounds__(256)
__global__ void transpose_w(const float* __restrict__ W, __hip_bfloat16* __restrict__ Wt,
                            int K, int N) {
    __shared__ float tile[64][65];
    const int k0 = blockIdx.x * 64;
    const int n0 = blockIdx.y * 64;
    const int tid = threadIdx.x;
    const int c = tid & 63;
    const int r0 = (tid >> 6) * 16;
    #pragma unroll
    for (int i = 0; i < 16; ++i)
        tile[r0 + i][c] = W[(size_t)(k0 + r0 + i) * N + n0 + c];
    __syncthreads();
    #pragma unroll
    for (int i = 0; i < 16; ++i)
        Wt[(size_t)(n0 + r0 + i) * K + k0 + c] = __float2bfloat16(tile[c][r0 + i]);
}

__launch_bounds__(256)
__global__ void concat_bias(const float* __restrict__ bq, const float* __restrict__ bk,
                            const float* __restrict__ bv, float* __restrict__ o) {
    const int i = blockIdx.x * 256 + threadIdx.x;
    if (i < C_DIM) {
        o[i] = bq[i];
        o[C_DIM + i] = bk[i];
        o[2 * C_DIM + i] = bv[i];
    }
}

__launch_bounds__(256)
__global__ void f32_to_bf16_vec(const float* __restrict__ in, __hip_bfloat16* __restrict__ out,
                                int n4) {
    const int i = blockIdx.x * 256 + threadIdx.x;
    if (i < n4) {
        const float4 v = *reinterpret_cast<const float4*>(&in[(size_t)i * 4]);
        ushort4 u;
        u.x = __bfloat16_as_ushort(__float2bfloat16(v.x));
        u.y = __bfloat16_as_ushort(__float2bfloat16(v.y));
        u.z = __bfloat16_as_ushort(__float2bfloat16(v.z));
        u.w = __bfloat16_as_ushort(__float2bfloat16(v.w));
        *reinterpret_cast<ushort4*>(&out[(size_t)i * 4]) = u;
    }
}

// ---------------------------------------------------------------------------
// bf16 MFMA GEMM, m97 structure (verified R3/R4): 128x128 tile, BK=64.
// MODE 0: f32 out + bias. MODE 1: bf16 out + bias + exact GELU.
// MODE 2: QKV split: q (bf16, * QSCALE) / k (bf16) / vt (bf16 transposed).
// ---------------------------------------------------------------------------
#define GBM 128
#define GBN 128
#define GBK 64

template<int MODE>
__launch_bounds__(256)
__global__ void gemm_mfma(const __hip_bfloat16* __restrict__ A,
                          const __hip_bfloat16* __restrict__ Bt,
                          const float* __restrict__ bias,
                          float* __restrict__ outf,
                          __hip_bfloat16* __restrict__ outq,
                          __hip_bfloat16* __restrict__ outk,
                          __hip_bfloat16* __restrict__ outvt,
                          int M, int N, int K) {
    __shared__ __hip_bfloat16 As[GBM][GBK];   // 16 KB
    __shared__ __hip_bfloat16 Bs[GBN][GBK];   // 16 KB

    const int tid = threadIdx.x;
    const int l   = tid & 63;
    const int w   = tid >> 6;
    const int lr  = l & 15;
    const int lg  = l >> 4;
    const int wr  = w >> 1;
    const int wc  = w & 1;
    const int bm  = blockIdx.y * GBM;
    const int bn  = blockIdx.x * GBN;

    const int srow  = l >> 3;        // 0..7 row within 8-row chunk
    const int skoff = (l & 7) * 8;   // bf16 k-offset

    f32x4 acc[4][4];
    #pragma unroll
    for (int m = 0; m < 4; ++m)
        #pragma unroll
        for (int n = 0; n < 4; ++n)
            acc[m][n] = {0.f, 0.f, 0.f, 0.f};

    for (int k0 = 0; k0 < K; k0 += GBK) {
        if (k0) __syncthreads();
        #pragma unroll
        for (int i = 0; i < 4; ++i) {
            const int rb = (w * 4 + i) * 8;
            gload_lds16(&A[(size_t)(bm + rb + srow) * K + k0 + skoff], &As[rb][0]);
            gload_lds16(&Bt[(size_t)(bn + rb + srow) * K + k0 + skoff], &Bs[rb][0]);
        }
        __syncthreads();

        #pragma unroll
        for (int kk = 0; kk < 2; ++kk) {
            short8 af[4], bf[4];
            #pragma unroll
            for (int m = 0; m < 4; ++m)
                af[m] = *reinterpret_cast<const short8*>(&As[wr * 64 + m * 16 + lr][kk * 32 + lg * 8]);
            #pragma unroll
            for (int n = 0; n < 4; ++n)
                bf[n] = *reinterpret_cast<const short8*>(&Bs[wc * 64 + n * 16 + lr][kk * 32 + lg * 8]);
            #pragma unroll
            for (int m = 0; m < 4; ++m)
                #pragma unroll
                for (int n = 0; n < 4; ++n)
                    acc[m][n] = __builtin_amdgcn_mfma_f32_16x16x32_bf16(af[m], bf[n], acc[m][n], 0, 0, 0);
        }
    }

    #pragma unroll
    for (int m = 0; m < 4; ++m) {
        #pragma unroll
        for (int rr = 0; rr < 4; ++rr) {
            const int row = bm + wr * 64 + m * 16 + lg * 4 + rr;
            #pragma unroll
            for (int n = 0; n < 4; ++n) {
                const int col = bn + wc * 64 + n * 16 + lr;
                float v = acc[m][n][rr] + bias[col];
                if constexpr (MODE == 0) {
                    outf[(size_t)row * N + col] = v;
                } else if constexpr (MODE == 1) {
                    v = 0.5f * v * (1.0f + erff(v * 0.70710678118654752f));
                    outq[(size_t)row * N + col] = __float2bfloat16(v);
                } else {
                    if (col < C_DIM)
                        outq[(size_t)row * C_DIM + col] = __float2bfloat16(v * QSCALE);
                    else if (col < 2 * C_DIM)
                        outk[(size_t)row * C_DIM + (col - C_DIM)] = __float2bfloat16(v);
                    else
                        outvt[(size_t)(col - 2 * C_DIM) * T_SEQ + row] = __float2bfloat16(v);
                }
            }
        }
    }
}

// ---------------------------------------------------------------------------
// Flash attention, bf16 MFMA. QBLK=64 (4 waves x 16 q-rows), KVB=128.
// LDS physical layout identical to R4-verified kernel; NEW in R5:
//  - double-buffered K/V with 2-phase prefetch (T3-minimum: STAGE(t+1) before
//    compute(t), one __syncthreads per tile whose implicit vmcnt(0) drains)
//  - defer-max online softmax (T13): per-lane local max, cross-lane reduce +
//    O-rescale only when __all(pmax - m <= 8) fails; l kept as per-lane
//    partial, reduced once at the end.
//  - s_setprio(1) around MFMA clusters (T5).
//   Ks  [2][128][64] : slot(16B) ^= row&7
//   Vts [2][64][128] : slot ^= row&15
//   Ps  [4][16][128] : slot ^= qrow
// ---------------------------------------------------------------------------
#define QBLK 64
#define KVB 128

__launch_bounds__(256)
__global__ void attn_mfma(const __hip_bfloat16* __restrict__ q,
                          const __hip_bfloat16* __restrict__ k,
                          const __hip_bfloat16* __restrict__ vt,
                          __hip_bfloat16* __restrict__ o) {
    __shared__ __hip_bfloat16 Ks[2][KVB][64];
    __shared__ __hip_bfloat16 Vts[2][D_HEAD][KVB];
    __shared__ __hip_bfloat16 Ps[4][16][KVB];

    const int tid  = threadIdx.x;
    const int wid  = tid >> 6;
    const int lane = tid & 63;
    const int lr   = lane & 15;
    const int lg   = lane >> 4;

    const int h  = blockIdx.x;
    const int q0 = T_SEQ - QBLK - blockIdx.y * QBLK;  // heavy blocks dispatch first
    const int qw = q0 + wid * 16;

    // staging decomposition (verified R4)
    const int ksrc = 8 * ((lane & 7) ^ (lane >> 3));
    const int kr   = lane >> 3;
    const int vr   = lane >> 4;
    const int vs   = lane & 15;

    // Q fragments in registers (pre-scaled by QSCALE in the QKV epilogue)
    short8 aq[2];
    #pragma unroll
    for (int kk = 0; kk < 2; ++kk)
        aq[kk] = *reinterpret_cast<const short8*>(
            &q[(size_t)(qw + lr) * C_DIM + h * D_HEAD + kk * 32 + lg * 8]);

    f32x4 o_acc[4];
    #pragma unroll
    for (int dc = 0; dc < 4; ++dc) o_acc[dc] = {0.f, 0.f, 0.f, 0.f};
    float m_run[4], l_part[4];
    #pragma unroll
    for (int r = 0; r < 4; ++r) { m_run[r] = -1e30f; l_part[r] = 0.f; }

    auto stage = [&](int buf, int s0) {
        #pragma unroll
        for (int i = 0; i < 4; ++i) {
            const int rb = wid * 32 + i * 8;
            gload_lds16(&k[(size_t)(s0 + rb + kr) * C_DIM + h * D_HEAD + ksrc],
                        &Ks[buf][rb][0]);
        }
        #pragma unroll
        for (int i = 0; i < 4; ++i) {
            const int vb = wid * 16 + i * 4;
            const int vsrc = 8 * (vs ^ (i * 4 + vr));
            gload_lds16(&vt[(size_t)(h * D_HEAD + vb + vr) * T_SEQ + s0 + vsrc],
                        &Vts[buf][vb][0]);
        }
    };

    const int n_tiles = (q0 + QBLK + KVB - 1) / KVB;

    stage(0, 0);
    __syncthreads();   // drain vmcnt: tile 0 resident

    for (int t = 0; t < n_tiles; ++t) {
        const int cur = t & 1;
        // prefetch next tile into the other buffer (flies under compute)
        if (t + 1 < n_tiles) stage(cur ^ 1, (t + 1) * KVB);

        // --- S = Q K^T (base-2-scaled), 8 column tiles ---
        f32x4 s_acc[8];
        __builtin_amdgcn_s_setprio(1);
        #pragma unroll
        for (int c = 0; c < 8; ++c) {
            s_acc[c] = {0.f, 0.f, 0.f, 0.f};
            #pragma unroll
            for (int kk = 0; kk < 2; ++kk) {
                const short8 bk8 = *reinterpret_cast<const short8*>(
                    &Ks[cur][c * 16 + lr][8 * ((4 * kk + lg) ^ (lr & 7))]);
                s_acc[c] = __builtin_amdgcn_mfma_f32_16x16x32_bf16(aq[kk], bk8, s_acc[c], 0, 0, 0);
            }
        }
        __builtin_amdgcn_s_setprio(0);

        // causal mask (last tile only)
        if (t == n_tiles - 1) {
            const int s0 = t * KVB;
            #pragma unroll
            for (int c = 0; c < 8; ++c)
                #pragma unroll
                for (int r = 0; r < 4; ++r) {
                    const int sg = s0 + c * 16 + lr;
                    const int qg = qw + lg * 4 + r;
                    if (sg > qg) s_acc[c][r] = -1e30f;
                }
        }

        // --- defer-max online softmax (base-2) ---
        float pm[4];
        #pragma unroll
        for (int r = 0; r < 4; ++r) {
            const float m0 = fmaxf(fmaxf(s_acc[0][r], s_acc[1][r]),
                                   fmaxf(s_acc[2][r], s_acc[3][r]));
            const float m1 = fmaxf(fmaxf(s_acc[4][r], s_acc[5][r]),
                                   fmaxf(s_acc[6][r], s_acc[7][r]));
            pm[r] = fmaxf(m0, m1);
        }
        const float need = fmaxf(fmaxf(pm[0] - m_run[0], pm[1] - m_run[1]),
                                 fmaxf(pm[2] - m_run[2], pm[3] - m_run[3]));
        if (!__all(need <= 8.0f)) {   // rare after first tile
            #pragma unroll
            for (int r = 0; r < 4; ++r) {
                float nm = pm[r];
                #pragma unroll
                for (int off = 1; off < 16; off <<= 1)
                    nm = fmaxf(nm, __shfl_xor(nm, off));
                nm = fmaxf(nm, m_run[r]);
                const float corr = __builtin_amdgcn_exp2f(m_run[r] - nm);
                m_run[r] = nm;
                l_part[r] *= corr;
                #pragma unroll
                for (int dc = 0; dc < 4; ++dc) o_acc[dc][r] *= corr;
            }
        }
        // exp2 + P write (swizzled) + per-lane partial row sums
        #pragma unroll
        for (int r = 0; r < 4; ++r) {
            const int qrow = lg * 4 + r;
            float ls = 0.f;
            #pragma unroll
            for (int c = 0; c < 8; ++c) {
                const float pv = __builtin_amdgcn_exp2f(s_acc[c][r] - m_run[r]);
                ls += pv;
                const int slot = (2 * c + (lr >> 3)) ^ qrow;
                Ps[wid][qrow][slot * 8 + (lr & 7)] = __float2bfloat16(pv);
            }
            l_part[r] += ls;
        }

        // --- PV: O += P V ---
        short8 ap[4];
        #pragma unroll
        for (int kk = 0; kk < 4; ++kk)
            ap[kk] = *reinterpret_cast<const short8*>(
                &Ps[wid][lr][8 * ((4 * kk + lg) ^ lr)]);
        __builtin_amdgcn_s_setprio(1);
        #pragma unroll
        for (int dc = 0; dc < 4; ++dc)
            #pragma unroll
            for (int kk = 0; kk < 4; ++kk) {
                const short8 bv8 = *reinterpret_cast<const short8*>(
                    &Vts[cur][dc * 16 + lr][8 * ((4 * kk + lg) ^ lr)]);
                o_acc[dc] = __builtin_amdgcn_mfma_f32_16x16x32_bf16(ap[kk], bv8, o_acc[dc], 0, 0, 0);
            }
        __builtin_amdgcn_s_setprio(0);

        __syncthreads();   // drains prefetch vmcnt + guards buffer swap & Ps WAR
    }

    // final cross-lane row-sum reduce (once per block, not per tile)
    #pragma unroll
    for (int r = 0; r < 4; ++r) {
        #pragma unroll
        for (int off = 1; off < 16; off <<= 1)
            l_part[r] += __shfl_xor(l_part[r], off);
    }

    #pragma unroll
    for (int dc = 0; dc < 4; ++dc)
        #pragma unroll
        for (int r = 0; r < 4; ++r)
            o[(size_t)(qw + lg * 4 + r) * C_DIM + h * D_HEAD + dc * 16 + lr] =
                __float2bfloat16(o_acc[dc][r] / l_part[r]);
}

// ---------------------------------------------------------------------------
// Fused residual add + LayerNorm; optional bf16 secondary output.
// ---------------------------------------------------------------------------
template<bool WB16>
__launch_bounds__(256)
__global__ void add_ln(const float* __restrict__ a, const float* __restrict__ b,
                       const float* __restrict__ g, const float* __restrict__ beta,
                       float* __restrict__ outf, __hip_bfloat16* __restrict__ outb) {
    const int row = blockIdx.x;
    const int tid = threadIdx.x;
    const size_t rb = (size_t)row * C_DIM;

    float x[3];
    #pragma unroll
    for (int i = 0; i < 3; ++i) {
        const int c = tid + 256 * i;
        x[i] = a[rb + c] + b[rb + c];
    }

    float s = x[0] + x[1] + x[2];
    float s2 = x[0] * x[0] + x[1] * x[1] + x[2] * x[2];

    #pragma unroll
    for (int off = 32; off; off >>= 1) {
        s  += __shfl_xor(s, off);
        s2 += __shfl_xor(s2, off);
    }

    __shared__ float red[10];
    const int wave = tid >> 6;
    const int lane = tid & 63;
    if (lane == 0) { red[wave] = s; red[4 + wave] = s2; }
    __syncthreads();
    if (tid == 0) {
        const float ts  = red[0] + red[1] + red[2] + red[3];
        const float ts2 = red[4] + red[5] + red[6] + red[7];
        const float mu = ts * (1.0f / C_DIM);
        const float var = ts2 * (1.0f / C_DIM) - mu * mu;
        red[8] = mu;
        red[9] = rsqrtf(var + EPS);
    }
    __syncthreads();
    const float mu = red[8];
    const float rstd = red[9];

    #pragma unroll
    for (int i = 0; i < 3; ++i) {
        const int c = tid + 256 * i;
        const float v = (x[i] - mu) * rstd * g[c] + beta[c];
        outf[rb + c] = v;
        if constexpr (WB16) outb[rb + c] = __float2bfloat16(v);
    }
}

// ---------------------------------------------------------------------------
extern "C" void kernel_launch(void* const* d_in, const int* in_sizes, int n_in,
                              void* d_out, int out_size, void* d_ws, size_t ws_size,
                              hipStream_t stream) {
    const float* x     = (const float*)d_in[0];
    const float* Wq    = (const float*)d_in[1];
    const float* bq    = (const float*)d_in[2];
    const float* Wk    = (const float*)d_in[3];
    const float* bk    = (const float*)d_in[4];
    const float* Wv    = (const float*)d_in[5];
    const float* bv    = (const float*)d_in[6];
    const float* Wo    = (const float*)d_in[7];
    const float* bo    = (const float*)d_in[8];
    const float* ln1_g = (const float*)d_in[9];
    const float* ln1_b = (const float*)d_in[10];
    const float* W1    = (const float*)d_in[11];
    const float* b1    = (const float*)d_in[12];
    const float* W2    = (const float*)d_in[13];
    const float* b2    = (const float*)d_in[14];
    const float* ln2_g = (const float*)d_in[15];
    const float* ln2_b = (const float*)d_in[16];

    float* out = (float*)d_out;

    // --- workspace arena (bytes) ---
    char* wsb = (char*)d_ws;
    const size_t TCb16 = (size_t)T_SEQ * C_DIM * 2;          // 6,291,456
    __hip_bfloat16* xb  = (__hip_bfloat16*)(wsb);
    __hip_bfloat16* qb  = (__hip_bfloat16*)(wsb + TCb16);
    __hip_bfloat16* kb  = (__hip_bfloat16*)(wsb + 2 * TCb16);
    __hip_bfloat16* vtb = (__hip_bfloat16*)(wsb + 3 * TCb16);
    __hip_bfloat16* mid = (__hip_bfloat16*)(wsb);            // [T][F] bf16 overlays A
    float* proj = (float*)(wsb + 4 * TCb16);
    float* mlpo = proj;
    __hip_bfloat16* obuf = (__hip_bfloat16*)(wsb + 4 * TCb16 + 12582912);
    __hip_bfloat16* hb   = obuf;
    float* hbuf = (float*)(wsb + 4 * TCb16 + 12582912 + TCb16);
    char* we = wsb + 4 * TCb16 + 12582912 + TCb16 + 12582912;
    __hip_bfloat16* Wqkv_t = (__hip_bfloat16*)(we);                       // [2304][768]
    __hip_bfloat16* Wo_t   = (__hip_bfloat16*)(we + 3538944);             // [768][768]
    __hip_bfloat16* W1_t   = (__hip_bfloat16*)(we + 3538944 + 1179648);   // [3072][768]
    __hip_bfloat16* W2_t   = (__hip_bfloat16*)(we + 3538944 + 1179648 + 4718592); // [768][3072]
    float* bqkv            = (float*)(we + 3538944 + 1179648 + 2 * 4718592);

    const dim3 blk256(256);

    // --- weight prep (all independent) ---
    transpose_w<<<dim3(12, 12), blk256, 0, stream>>>(Wq, Wqkv_t,                   C_DIM, C_DIM);
    transpose_w<<<dim3(12, 12), blk256, 0, stream>>>(Wk, Wqkv_t + (size_t)C_DIM * C_DIM,     C_DIM, C_DIM);
    transpose_w<<<dim3(12, 12), blk256, 0, stream>>>(Wv, Wqkv_t + (size_t)2 * C_DIM * C_DIM, C_DIM, C_DIM);
    transpose_w<<<dim3(12, 12), blk256, 0, stream>>>(Wo, Wo_t, C_DIM, C_DIM);
    transpose_w<<<dim3(12, 48), blk256, 0, stream>>>(W1, W1_t, C_DIM, F_DIM);
    transpose_w<<<dim3(48, 12), blk256, 0, stream>>>(W2, W2_t, F_DIM, C_DIM);
    concat_bias<<<dim3(3), blk256, 0, stream>>>(bq, bk, bv, bqkv);
    f32_to_bf16_vec<<<dim3(3072), blk256, 0, stream>>>(x, xb, T_SEQ * C_DIM / 4);

    // --- fused QKV GEMM: [T,768] @ [768,2304], epilogue splits q/k/vt ---
    gemm_mfma<2><<<dim3(3 * C_DIM / GBN, T_SEQ / GBM), blk256, 0, stream>>>(
        xb, Wqkv_t, bqkv, nullptr, qb, kb, vtb, T_SEQ, 3 * C_DIM, C_DIM);

    // --- flash attention (head-major grid for L2 locality) ---
    attn_mfma<<<dim3(N_HEADS, T_SEQ / QBLK), blk256, 0, stream>>>(qb, kb, vtb, obuf);

    // --- output projection -> f32 proj ---
    gemm_mfma<0><<<dim3(C_DIM / GBN, T_SEQ / GBM), blk256, 0, stream>>>(
        obuf, Wo_t, bo, proj, nullptr, nullptr, nullptr, T_SEQ, C_DIM, C_DIM);

    // --- h = LN(x + proj): f32 + bf16 ---
    add_ln<true><<<dim3(T_SEQ), blk256, 0, stream>>>(x, proj, ln1_g, ln1_b, hbuf, hb);

    // --- MLP1: gelu(h @ W1 + b1) -> bf16 mid ---
    gemm_mfma<1><<<dim3(F_DIM / GBN, T_SEQ / GBM), blk256, 0, stream>>>(
        hb, W1_t, b1, nullptr, mid, nullptr, nullptr, T_SEQ, F_DIM, C_DIM);

    // --- MLP2: mid @ W2 + b2 -> f32 mlpo ---
    gemm_mfma<0><<<dim3(C_DIM / GBN, T_SEQ / GBM), blk256, 0, stream>>>(
        mid, W2_t, b2, mlpo, nullptr, nullptr, nullptr, T_SEQ, C_DIM, F_DIM);

    // --- y = LN(h + mlpo) ---
    add_ln<false><<<dim3(T_SEQ), blk256, 0, stream>>>(hbuf, mlpo, ln2_g, ln2_b, out, nullptr);
}